// Round 1
// 257.329 us; speedup vs baseline: 1.0037x; 1.0037x over previous
//
#include <hip/hip_runtime.h>

// Mandelbrot counts — R6-proven bit-exact arithmetic + compaction + wave-
// aggregated enqueue (R8), now with wave-coherent ballot early-exit (R9).
//
// R8 forensics: stage A 105us @ VALUBusy 77%, HBM 20% -> VALU-issue bound.
// Stage B just under ~105us. Both stages run FIXED trip counts:
//   * A: 16 checks for everyone, incl. cardioid/bulb interior (~22% of
//     pixels) and far-field waves fully escaped by iter 2-4.
//   * B: 240 checks per record; WRITE_SIZE says ~1.9M records of which
//     ~80% are boundary pixels with mean remaining life of a few tens of
//     iters. ~460M iterations issued, ~100M live.
// Queue is packed in wave order from adjacent pixels -> escape times are
// wave-coherent -> ballot early-exit converts lane-deadness into cycles:
//   for each chunk: if (__ballot(act!=0)==0) break;  (~1 v_cmp / chunk)
// Also: act is pre-zeroed for shortcut lanes so pure-interior waves skip
// ALL iteration work. Exactness unchanged: exit only fires when no lane is
// active, i.e. every cnt in the wave is already final.
//
// Proven iter body (absmax=0 in R6/R7/R8), pinned with inline asm:
//   zi2 = fl32(zi*zi); mag = fma(zr,zr,zi2)
//   nr  = fl32(fma(zr,zr,-zi2) + cr); zi' = fma(2*zr, zi, ci)
// Cardioid/bulb shortcut margin 1e-3 (HW-validated, absmax=0).
//
// d_ws: [0,4096) 64 counters (stride 64B) | q1: float4 recs, seg-major
// (seg*seg_cap+slot) | q2: int idx. Segment overflow -> finish inline
// (correct, slower). Tiny ws -> monolithic fallback. Queue order is
// nondeterministic but per-pixel values are deterministic.

#define MAX_ITERS 256

__device__ __forceinline__ float mul32(float a, float b) {
    float d; asm("v_mul_f32 %0, %1, %2" : "=v"(d) : "v"(a), "v"(b)); return d;
}
__device__ __forceinline__ float add32(float a, float b) {
    float d; asm("v_add_f32 %0, %1, %2" : "=v"(d) : "v"(a), "v"(b)); return d;
}
__device__ __forceinline__ float fma32(float a, float b, float c) {
    float d; asm("v_fma_f32 %0, %1, %2, %3" : "=v"(d) : "v"(a), "v"(b), "v"(c)); return d;
}
__device__ __forceinline__ float fma32_negc(float a, float b, float c) {
    float d; asm("v_fma_f32 %0, %1, %2, -%3" : "=v"(d) : "v"(a), "v"(b), "v"(c)); return d;
}

__device__ __forceinline__ void iter_checks(float cr, float ci,
                                            float& zr, float& zi,
                                            float& act, float& cnt, int nchecks)
{
    #pragma unroll 8
    for (int s = 0; s < nchecks; ++s) {
        const float zi2 = mul32(zi, zi);
        const float mag = fma32(zr, zr, zi2);
        act = (mag < 4.0f) ? act : 0.0f;      // sticky escape, NaN-safe
        cnt = cnt + act;                      // exact small-int add
        const float t   = fma32_negc(zr, zr, zi2);
        const float nr  = add32(t, cr);
        const float t2  = add32(zr, zr);
        zi = fma32(t2, zi, ci);
        zr = nr;
    }
}

// Wave-coherent early exit: run CHUNK checks at a time; once NO lane in the
// wave is still active, every cnt is final and the remaining checks are
// dead work -> break. Exactness: identical to running all checks.
template <int CHUNK>
__device__ __forceinline__ void iter_until_dead(float cr, float ci,
                                                float& zr, float& zi,
                                                float& act, float& cnt,
                                                int nchunks)
{
    for (int c = 0; c < nchunks; ++c) {
        if (__ballot(act != 0.0f) == 0ull) break;
        iter_checks(cr, ci, zr, zi, act, cnt, CHUNK);
    }
}

__global__ void zero_ctrs(unsigned char* ws) {
    if (threadIdx.x < 64) *(unsigned*)(ws + (size_t)threadIdx.x * 64u) = 0u;
}

__global__ __launch_bounds__(256) void mandel_stage_a(
    const float* __restrict__ c_real, const float* __restrict__ c_imag,
    float* __restrict__ out, unsigned char* __restrict__ ws,
    unsigned seg_cap, int n)
{
    int i = blockIdx.x * blockDim.x + threadIdx.x;
    if (i >= n) return;
    const float cr = c_real[i];
    const float ci = c_imag[i];

    // Closed-form safe-interior shortcut (margin absorbs any rounding).
    const float xq = cr - 0.25f;
    const float q  = xq * xq + ci * ci;
    const bool in_card = (q * (q + xq) - 0.25f * ci * ci) < -1e-3f;
    const float xb = cr + 1.0f;
    const bool in_bulb = (xb * xb + ci * ci) < (0.0625f - 1e-3f);
    const bool shortcut = in_card | in_bulb;

    // act pre-zeroed for shortcut lanes: they never escape, so they'd pin
    // the wave's ballot at "alive" for all 16 checks. Their cnt stays 0 and
    // out is written as 256 below, so this is value-neutral.
    float zr = cr, zi = ci, cnt = 0.0f;
    float act = shortcut ? 0.0f : 1.0f;
    iter_until_dead<4>(cr, ci, zr, zi, act, cnt, 4);  // checks z_0..z_15

    const bool surv = (act != 0.0f);

    // Wave-aggregated enqueue: one atomic per wave, striped over 64 counters.
    const unsigned long long m = __ballot(surv);
    if (m != 0ull) {
        const int lane = __builtin_amdgcn_mbcnt_hi(
            ~0u, __builtin_amdgcn_mbcnt_lo(~0u, 0));
        const int leader = (int)__ffsll((unsigned long long)m) - 1;
        const int seg = blockIdx.x & 63;
        unsigned* ctr = (unsigned*)(ws + (size_t)seg * 64u);
        unsigned base = 0u;
        if (lane == leader) base = atomicAdd(ctr, (unsigned)__popcll(m));
        base = (unsigned)__shfl((int)base, leader, 64);
        if (surv) {
            const unsigned rank = (unsigned)__popcll(m & ((1ull << lane) - 1ull));
            const unsigned slot = base + rank;
            if (slot < seg_cap) {
                float4* q1 = (float4*)(ws + 4096);
                int*    q2 = (int*)(ws + 4096 + (size_t)seg_cap * 64u * 16u);
                const size_t p = (size_t)seg * seg_cap + slot;
                q1[p] = make_float4(zr, zi, cr, ci);
                q2[p] = i;
                return;
            }
            // overflow: finish inline (checks z_16..z_255), early-exit too
            iter_until_dead<8>(cr, ci, zr, zi, act, cnt, 30);
            out[i] = cnt;
            return;
        }
    }
    out[i] = shortcut ? 256.0f : cnt;
}

__global__ __launch_bounds__(256) void mandel_stage_b(
    float* __restrict__ out, const unsigned char* __restrict__ ws,
    unsigned seg_cap, int blocks_per_seg)
{
    const int seg = (int)(blockIdx.x & 63u);
    const int grp = (int)(blockIdx.x >> 6);
    const unsigned cnt_s = *(const unsigned*)(ws + (size_t)seg * 64u);
    const unsigned nq = (cnt_s < seg_cap) ? cnt_s : seg_cap;
    const float4* q1 = (const float4*)(ws + 4096);
    const int*    q2 = (const int*)(ws + 4096 + (size_t)seg_cap * 64u * 16u);
    const unsigned stride = (unsigned)blocks_per_seg * 256u;
    for (unsigned j = (unsigned)grp * 256u + threadIdx.x; j < nq; j += stride) {
        const size_t p = (size_t)seg * seg_cap + j;
        const float4 rec = q1[p];
        const int idx = q2[p];
        float zr = rec.x, zi = rec.y;
        const float cr = rec.z, ci = rec.w;
        float act = 1.0f, cnt = 16.0f;
        // checks z_16..z_255; records are wave-order-packed from adjacent
        // pixels -> escape times coherent -> ballot-exit pays off.
        iter_until_dead<8>(cr, ci, zr, zi, act, cnt, 30);
        out[idx] = cnt;
    }
}

// Fallback: monolithic kernel (used only if d_ws is tiny), with early exit.
__global__ __launch_bounds__(256) void mandel_mono(
    const float* __restrict__ c_real, const float* __restrict__ c_imag,
    float* __restrict__ out, int n)
{
    int i = blockIdx.x * blockDim.x + threadIdx.x;
    if (i >= n) return;
    const float cr = c_real[i], ci = c_imag[i];
    float zr = cr, zi = ci, act = 1.0f, cnt = 0.0f;
    iter_until_dead<8>(cr, ci, zr, zi, act, cnt, 32);
    out[i] = cnt;
}

extern "C" void kernel_launch(void* const* d_in, const int* in_sizes, int n_in,
                              void* d_out, int out_size, void* d_ws, size_t ws_size,
                              hipStream_t stream)
{
    const float* c_real = (const float*)d_in[0];
    const float* c_imag = (const float*)d_in[1];
    float* out = (float*)d_out;
    const int n = in_sizes[0];  // 4096*4096
    const int block = 256;
    const int gridA = (n + block - 1) / block;

    unsigned char* ws = (unsigned char*)d_ws;
    const size_t avail = (ws_size > 4096) ? (ws_size - 4096) : 0;
    unsigned seg_cap = (unsigned)(avail / (64u * 20u));  // 20B/record, 64 segs

    if (seg_cap < 1024u) {  // ws too small for compaction: proven fallback
        mandel_mono<<<gridA, block, 0, stream>>>(c_real, c_imag, out, n);
        return;
    }

    zero_ctrs<<<1, 64, 0, stream>>>(ws);
    mandel_stage_a<<<gridA, block, 0, stream>>>(c_real, c_imag, out, ws,
                                                seg_cap, n);
    const int blocks_per_seg = 256;  // 64*256 = 16384 blocks, 64k threads/seg
    mandel_stage_b<<<64 * blocks_per_seg, block, 0, stream>>>(out, ws, seg_cap,
                                                              blocks_per_seg);
}